// Round 1
// 9407.262 us; speedup vs baseline: 2.7535x; 2.7535x over previous
//
#include <hip/hip_runtime.h>

// TrainerRNN: 10-layer GRU (T=2048, IN=384, H=768) + linear head (384).
// ROUND 6: single-phase 10-layer wavefront pipeline (lag 2 between layers).
// R5 spent 5 phases x 2050 = 10250 global-barrier ticks @2.5us (barrier-
// latency bound, VALU 14%, HBM 0.7%). This round removes 4/5 of the ticks:
// all 10 layers run concurrently (240 blocks = 10 layers x 24 blocks x 32
// units), tau(l,t) = t + 2l + 1, NT = 2067 ticks total.
// Enablers:
//  - w_hh lives in VGPRs: 3 gates x 96-k slice = 288 fp32 regs/thread
//    (256 thr, 1 blk/CU -> 1 wave/SIMD -> 512-VGPR budget). No LDS, no
//    per-tick weight reads; critical GEMV = 24 b128 LDS h-reads + 288 FMA.
//  - w_ih lives in LDS as fp16 (96 rows x 776 halves = 145.5KB, padded for
//    bank spread). gi(t+1) computed in the arrive->wait shadow from
//    h_{l-1}[t+1], published at barrier m-1 (lag-2 => prefetch-safe, R4/R5
//    lesson). Shadow LLC loads issued at tick start (async split).
//  - 8-lane unit-groups: reduce = 3 shfl_xor rounds x 3 gates (9 ops) vs
//    full-wave 144.
// Coherence: unchanged R3/R5 scheme (relaxed AGENT sc1 atomics, syncthreads
// drains vmcnt before counter bump). Barrier: 60 padded LLC group counters
// (240 blocks / 4), wave 0 scans.

#define T_SEQ 2048
#define H_DIM 768
#define IN0   384
#define G3    2304
#define NLAYER 10
#define BPL   24                      // blocks per layer
#define NBLK  (NLAYER * BPL)          // 240
#define UPB   32                      // units per block
#define NTHR  256                     // 4 waves x 8 unit-groups x 8 lanes
#define NOUT  384
#define CTR_STRIDE 32                 // counters 128 B apart
#define NT    (T_SEQ + 2*(NLAYER-1) + 1)   // 2067 ticks
#define WIH_STRIDE 776                // 768 + 8 halves pad (row stride 1552B = 388dw = 4 mod 32)

typedef __attribute__((ext_vector_type(8))) _Float16 half8;

__device__ __forceinline__ float sigm(float x) { return 1.0f / (1.0f + __expf(-x)); }

__device__ __forceinline__ float ldg_dev(const float* p) {
    return __hip_atomic_load(p, __ATOMIC_RELAXED, __HIP_MEMORY_SCOPE_AGENT);
}
__device__ __forceinline__ void stg_dev(float* p, float v) {
    __hip_atomic_store(p, v, __ATOMIC_RELAXED, __HIP_MEMORY_SCOPE_AGENT);
}

extern "C" __global__ __launch_bounds__(NTHR, 1) void gru_pipe(
    const float* __restrict__ x,
    const float* __restrict__ wih0,
    const float* __restrict__ whh0,
    const float* __restrict__ bih0,
    const float* __restrict__ bhh0,
    const float* __restrict__ wihS,
    const float* __restrict__ whhS,
    const float* __restrict__ bihS,
    const float* __restrict__ bhhS,
    float* __restrict__ ring,          // 9 layers x 8 rows x 768
    float* __restrict__ h9,            // 2048 x 768 (layer 9 output)
    unsigned int* __restrict__ ctr)
{
    __shared__ _Float16 wih16[96 * WIH_STRIDE];   // 148,992 B
    __shared__ float    hstage[8 * 100];          //   3,200 B (96+4 pad per slice)
    __shared__ float    giring[2][UPB][3];        //     768 B

    const int tid  = threadIdx.x;
    const int lane = tid & 63;
    const int wv   = tid >> 6;         // 0..3
    const int g    = lane >> 3;        // unit-group in wave, 0..7
    const int p    = lane & 7;         // k-slice position, 0..7
    const int ulocal = wv * 8 + g;     // 0..31
    const int bid  = blockIdx.x;
    const int layer = bid / BPL;
    const int sub   = bid % BPL;
    const int uglob = sub * UPB + ulocal;          // 0..767
    const int Din   = layer ? H_DIM : IN0;

    const float* wihL = layer ? wihS + (size_t)(layer - 1) * G3 * H_DIM : wih0;
    const float* whhL = layer ? whhS + (size_t)(layer - 1) * G3 * H_DIM : whh0;
    const float* bihL = layer ? bihS + (size_t)(layer - 1) * G3 : bih0;
    const float* bhhL = layer ? bhhS + (size_t)(layer - 1) * G3 : bhh0;

    // ---- prologue: w_hh -> VGPRs (lane's 96-k slice of its unit's 3 gate rows) ----
    float4 wr[3][24];
#pragma unroll
    for (int gate = 0; gate < 3; ++gate) {
        const float4* src = (const float4*)(whhL + (size_t)(uglob + gate * H_DIM) * H_DIM + 96 * p);
#pragma unroll
        for (int i = 0; i < 24; ++i) wr[gate][i] = src[i];
    }
    const float bhr  = bhhL[uglob], bhz = bhhL[uglob + H_DIM], bhn  = bhhL[uglob + 2 * H_DIM];
    const float bir  = bihL[uglob], biz = bihL[uglob + H_DIM], bin_ = bihL[uglob + 2 * H_DIM];

    // ---- prologue: w_ih -> LDS fp16 (row r = ulocal*3 + gate) ----
    for (int rr = 0; rr < 24; ++rr) {
        const int r = wv * 24 + rr;            // 0..95
        const int u = r / 3, G = r % 3;
        const float* src = wihL + (size_t)(sub * UPB + u + G * H_DIM) * Din;
        _Float16* dst = wih16 + r * WIH_STRIDE;
        for (int k = lane; k < Din; k += 64) dst[k] = (_Float16)src[k];
    }
    __syncthreads();

    unsigned int gstep = 0;

    for (int m = 0; m < NT; ++m) {
        const int t  = m - 2 * layer - 1;
        const int tn = t + 1;
        const bool act  = (t >= 0) && (t < T_SEQ);
        const bool shad = (tn >= 0) && (tn < T_SEQ);

        // ---- early-issue LLC loads (critical h(t-1) + shadow h_{l-1}(t+1));
        //      both published at barrier m-1, one LLC latency covers both ----
        float cv0 = 0.f, cv1 = 0.f, cv2 = 0.f;
        float sv0 = 0.f, sv1 = 0.f, sv2 = 0.f;
        if (act && t > 0) {
            const float* hr = (layer == NLAYER - 1)
                ? h9 + (size_t)(t - 1) * H_DIM
                : ring + (size_t)(layer * 8 + ((t - 1) & 7)) * H_DIM;
            cv0 = ldg_dev(hr + tid);
            cv1 = ldg_dev(hr + tid + 256);
            cv2 = ldg_dev(hr + tid + 512);
        }
        if (shad && layer) {
            const float* srow = ring + (size_t)((layer - 1) * 8 + (tn & 7)) * H_DIM;
            sv0 = ldg_dev(srow + tid);
            sv1 = ldg_dev(srow + tid + 256);
            sv2 = ldg_dev(srow + tid + 512);
        }

        // ---- critical: stage h(t-1), GEMV from register weights ----
        if (act && t > 0) {
            hstage[((tid      ) / 96) * 100 + ((tid      ) % 96)] = cv0;
            hstage[((tid + 256) / 96) * 100 + ((tid + 256) % 96)] = cv1;
            hstage[((tid + 512) / 96) * 100 + ((tid + 512) % 96)] = cv2;
        }
        __syncthreads();

        float ar = 0.f, az = 0.f, an = 0.f;
        if (act && t > 0) {
            const float4* hs = (const float4*)(hstage + p * 100);
#pragma unroll
            for (int i = 0; i < 24; ++i) {
                const float4 h4 = hs[i];
                ar += h4.x * wr[0][i].x + h4.y * wr[0][i].y + h4.z * wr[0][i].z + h4.w * wr[0][i].w;
                az += h4.x * wr[1][i].x + h4.y * wr[1][i].y + h4.z * wr[1][i].z + h4.w * wr[1][i].w;
                an += h4.x * wr[2][i].x + h4.y * wr[2][i].y + h4.z * wr[2][i].z + h4.w * wr[2][i].w;
            }
        }
        if (act) {
#pragma unroll
            for (int off = 1; off <= 4; off <<= 1) {
                ar += __shfl_xor(ar, off, 64);
                az += __shfl_xor(az, off, 64);
                an += __shfl_xor(an, off, 64);
            }
            if (p == 0) {
                const float hp = (t > 0) ? hstage[(uglob / 96) * 100 + (uglob % 96)] : 0.f;
                const float* gi = giring[t & 1][ulocal];
                const float r = sigm(ar + bhr + gi[0]);
                const float z = sigm(az + bhz + gi[1]);
                const float n = tanhf(gi[2] + r * (an + bhn));
                float* outrow = (layer == NLAYER - 1)
                    ? h9 + (size_t)t * H_DIM
                    : ring + (size_t)(layer * 8 + (t & 7)) * H_DIM;
                stg_dev(outrow + uglob, (1.f - z) * n + z * hp);
            }
        }

        // ---- arrive (syncthreads drains sc1 stores via vmcnt(0)) ----
        __syncthreads();
        ++gstep;
        if (tid == 0)
            __hip_atomic_fetch_add(&ctr[(bid >> 2) * CTR_STRIDE], 1u,
                                   __ATOMIC_RELAXED, __HIP_MEMORY_SCOPE_AGENT);

        // ---- shadow: gi(t+1) = w_ih(fp16, LDS) . h_{l-1}(t+1)  (+ b_ih) ----
        if (shad) {
            if (layer) {
                hstage[((tid      ) / 96) * 100 + ((tid      ) % 96)] = sv0;
                hstage[((tid + 256) / 96) * 100 + ((tid + 256) % 96)] = sv1;
                hstage[((tid + 512) / 96) * 100 + ((tid + 512) % 96)] = sv2;
            } else {
                for (int k = tid; k < IN0; k += NTHR)
                    hstage[(k / 48) * 52 + (k % 48)] = x[(size_t)tn * IN0 + k];
            }
            __syncthreads();

            float sr = 0.f, sz = 0.f, sn = 0.f;
            if (layer) {
                const float4* hs = (const float4*)(hstage + p * 100);
                const half8* w0 = (const half8*)(wih16 + (ulocal * 3 + 0) * WIH_STRIDE + 96 * p);
                const half8* w1 = (const half8*)(wih16 + (ulocal * 3 + 1) * WIH_STRIDE + 96 * p);
                const half8* w2 = (const half8*)(wih16 + (ulocal * 3 + 2) * WIH_STRIDE + 96 * p);
#pragma unroll
                for (int i = 0; i < 12; ++i) {
                    const float4 ha = hs[2 * i], hb = hs[2 * i + 1];
                    const half8 a0 = w0[i], a1 = w1[i], a2 = w2[i];
                    sr += ha.x * (float)a0[0] + ha.y * (float)a0[1] + ha.z * (float)a0[2] + ha.w * (float)a0[3]
                        + hb.x * (float)a0[4] + hb.y * (float)a0[5] + hb.z * (float)a0[6] + hb.w * (float)a0[7];
                    sz += ha.x * (float)a1[0] + ha.y * (float)a1[1] + ha.z * (float)a1[2] + ha.w * (float)a1[3]
                        + hb.x * (float)a1[4] + hb.y * (float)a1[5] + hb.z * (float)a1[6] + hb.w * (float)a1[7];
                    sn += ha.x * (float)a2[0] + ha.y * (float)a2[1] + ha.z * (float)a2[2] + ha.w * (float)a2[3]
                        + hb.x * (float)a2[4] + hb.y * (float)a2[5] + hb.z * (float)a2[6] + hb.w * (float)a2[7];
                }
            } else {
                const float4* hs = (const float4*)(hstage + p * 52);
                const half8* w0 = (const half8*)(wih16 + (ulocal * 3 + 0) * WIH_STRIDE + 48 * p);
                const half8* w1 = (const half8*)(wih16 + (ulocal * 3 + 1) * WIH_STRIDE + 48 * p);
                const half8* w2 = (const half8*)(wih16 + (ulocal * 3 + 2) * WIH_STRIDE + 48 * p);
#pragma unroll
                for (int i = 0; i < 6; ++i) {
                    const float4 ha = hs[2 * i], hb = hs[2 * i + 1];
                    const half8 a0 = w0[i], a1 = w1[i], a2 = w2[i];
                    sr += ha.x * (float)a0[0] + ha.y * (float)a0[1] + ha.z * (float)a0[2] + ha.w * (float)a0[3]
                        + hb.x * (float)a0[4] + hb.y * (float)a0[5] + hb.z * (float)a0[6] + hb.w * (float)a0[7];
                    sz += ha.x * (float)a1[0] + ha.y * (float)a1[1] + ha.z * (float)a1[2] + ha.w * (float)a1[3]
                        + hb.x * (float)a1[4] + hb.y * (float)a1[5] + hb.z * (float)a1[6] + hb.w * (float)a1[7];
                    sn += ha.x * (float)a2[0] + ha.y * (float)a2[1] + ha.z * (float)a2[2] + ha.w * (float)a2[3]
                        + hb.x * (float)a2[4] + hb.y * (float)a2[5] + hb.z * (float)a2[6] + hb.w * (float)a2[7];
                }
            }
#pragma unroll
            for (int off = 1; off <= 4; off <<= 1) {
                sr += __shfl_xor(sr, off, 64);
                sz += __shfl_xor(sz, off, 64);
                sn += __shfl_xor(sn, off, 64);
            }
            if (p == 0) {
                float* gi = giring[tn & 1][ulocal];
                gi[0] = sr + bir;
                gi[1] = sz + biz;
                gi[2] = sn + bin_;
            }
        }

        // ---- wait: wave 0 scans 60 group counters ----
        if (wv == 0) {
            const unsigned int tgt = 4u * gstep;
            for (;;) {
                unsigned int v = 0xFFFFFFFFu;
                if (lane < NBLK / 4)
                    v = __hip_atomic_load(&ctr[lane * CTR_STRIDE],
                                          __ATOMIC_RELAXED, __HIP_MEMORY_SCOPE_AGENT);
                if (__all(v >= tgt)) break;
                __builtin_amdgcn_s_sleep(1);
            }
        }
        __syncthreads();
    }
}

extern "C" __global__ __launch_bounds__(NOUT, 1) void fc_head(
    const float* __restrict__ h,
    const float* __restrict__ fw,
    const float* __restrict__ fb,
    float* __restrict__ out)
{
    __shared__ float hs[H_DIM];
    const int t = blockIdx.x;
    const float* hr = h + (size_t)t * H_DIM;
    for (int k = threadIdx.x; k < H_DIM; k += NOUT) hs[k] = hr[k];
    __syncthreads();

    const int o = threadIdx.x;
    const float4* wr4 = (const float4*)(fw + (size_t)o * H_DIM);
    const float4* hs4 = (const float4*)hs;
    float acc = fb[o];
#pragma unroll 8
    for (int k = 0; k < H_DIM / 4; ++k) {
        const float4 w = wr4[k], hv = hs4[k];
        acc += w.x * hv.x + w.y * hv.y + w.z * hv.z + w.w * hv.w;
    }
    out[(size_t)t * NOUT + o] = acc;
}

extern "C" void kernel_launch(void* const* d_in, const int* in_sizes, int n_in,
                              void* d_out, int out_size, void* d_ws, size_t ws_size,
                              hipStream_t stream)
{
    const float* x    = (const float*)d_in[0];
    const float* wih0 = (const float*)d_in[1];
    const float* whh0 = (const float*)d_in[2];
    const float* bih0 = (const float*)d_in[3];
    const float* bhh0 = (const float*)d_in[4];
    const float* wihS = (const float*)d_in[5];
    const float* whhS = (const float*)d_in[6];
    const float* bihS = (const float*)d_in[7];
    const float* bhhS = (const float*)d_in[8];
    const float* fcw  = (const float*)d_in[9];
    const float* fcb  = (const float*)d_in[10];

    char* ws = (char*)d_ws;
    unsigned int* ctr = (unsigned int*)ws;                 // 64 KB counter region
    float* ring = (float*)(ws + 65536);                    // 9 x 8 x 768 fp32 = 221,184 B
    float* h9   = (float*)(ws + 65536 + 9 * 8 * H_DIM * 4);// 2048 x 768 fp32

    hipMemsetAsync(ctr, 0, 65536, stream);

    hipLaunchKernelGGL(gru_pipe, dim3(NBLK), dim3(NTHR), 0, stream,
                       x, wih0, whh0, bih0, bhh0, wihS, whhS, bihS, bhhS,
                       ring, h9, ctr);

    hipLaunchKernelGGL(fc_head, dim3(T_SEQ), dim3(NOUT), 0, stream,
                       h9, fcw, fcb, (float*)d_out);
}

// Round 2
// 8907.366 us; speedup vs baseline: 2.9080x; 1.0561x over previous
//
#include <hip/hip_runtime.h>

// TrainerRNN: 10-layer GRU (T=2048, IN=384, H=768) + linear head (384).
// ROUND 7: replace the per-tick GLOBAL barrier (R6: 2067 ticks x 4.55us,
// 240-block straggler sync + serial shadow + 60-counter scan) with
// per-layer producer/consumer DATAFLOW:
//  - each layer l has 6 sub-counters (4 blocks each), bumped once per row
//    after the row's slice stores drain (syncthreads vmcnt(0) discipline,
//    R3/R5/R6 scheme, relaxed AGENT atomics only).
//  - block (l,sub) at row t polls (single load, <=18 lines, per-lane tgts):
//      own layer  >= 4*t        (row t-1 complete)
//      layer l-1  >= 4*(t+2)    (row t+1 available for gi(t+1))
//      layer l+1  >= 4*(t-15)   (ring back-pressure, RING=16)
//  - gi(t+1) GEMV (fp16 w_ih in LDS) runs AFTER the bump -> overlaps the
//    bump->observe LLC round trip of the intra-layer cycle (a real shadow;
//    in lock-step R6 all blocks shadowed simultaneously so it hid nothing).
//  - straggler domain 240 -> ~48 blocks; inter-layer jitter absorbed by the
//    16-row ring instead of stalling the whole grid.
// w_hh stays in VGPRs (288 f32/thread), w_ih fp16 in LDS, 8-lane unit
// groups, 3-round shfl reduces -- unchanged from R6.

#define T_SEQ 2048
#define H_DIM 768
#define IN0   384
#define G3    2304
#define NLAYER 10
#define BPL   24                      // blocks per layer
#define NBLK  (NLAYER * BPL)          // 240
#define UPB   32                      // units per block
#define NTHR  256                     // 4 waves x 8 unit-groups x 8 lanes
#define NOUT  384
#define CTR_STRIDE 32                 // counters 128 B apart
#define RING  16                      // ring rows per layer
#define WIH_STRIDE 776                // 768 + 8 halves pad

typedef __attribute__((ext_vector_type(8))) _Float16 half8;

__device__ __forceinline__ float sigm(float x) { return 1.0f / (1.0f + __expf(-x)); }

__device__ __forceinline__ float ldg_dev(const float* p) {
    return __hip_atomic_load(p, __ATOMIC_RELAXED, __HIP_MEMORY_SCOPE_AGENT);
}
__device__ __forceinline__ void stg_dev(float* p, float v) {
    __hip_atomic_store(p, v, __ATOMIC_RELAXED, __HIP_MEMORY_SCOPE_AGENT);
}

extern "C" __global__ __launch_bounds__(NTHR, 1) void gru_flow(
    const float* __restrict__ x,
    const float* __restrict__ wih0,
    const float* __restrict__ whh0,
    const float* __restrict__ bih0,
    const float* __restrict__ bhh0,
    const float* __restrict__ wihS,
    const float* __restrict__ whhS,
    const float* __restrict__ bihS,
    const float* __restrict__ bhhS,
    float* __restrict__ ring,          // 9 layers x RING x 768
    float* __restrict__ h9,            // 2048 x 768 (layer 9 output)
    unsigned int* __restrict__ ctr)    // 60 padded sub-counters
{
    __shared__ _Float16 wih16[96 * WIH_STRIDE];   // 148,992 B
    __shared__ float    hc[8 * 100];              // critical h(t-1) stage
    __shared__ float    hsd[8 * 100];             // shadow h_{l-1}(t+1) / x stage

    const int tid  = threadIdx.x;
    const int lane = tid & 63;
    const int wv   = tid >> 6;         // 0..3
    const int g    = lane >> 3;        // unit-group in wave, 0..7
    const int p    = lane & 7;         // k-slice position, 0..7
    const int ulocal = wv * 8 + g;     // 0..31
    const int bid  = blockIdx.x;
    const int layer = bid / BPL;
    const int sub   = bid % BPL;
    const int uglob = sub * UPB + ulocal;          // 0..767
    const int Din   = layer ? H_DIM : IN0;

    const float* wihL = layer ? wihS + (size_t)(layer - 1) * G3 * H_DIM : wih0;
    const float* whhL = layer ? whhS + (size_t)(layer - 1) * G3 * H_DIM : whh0;
    const float* bihL = layer ? bihS + (size_t)(layer - 1) * G3 : bih0;
    const float* bhhL = layer ? bhhS + (size_t)(layer - 1) * G3 : bhh0;

    // ---- prologue: w_hh -> VGPRs (lane's 96-k slice of its unit's 3 gate rows) ----
    float4 wr[3][24];
#pragma unroll
    for (int gate = 0; gate < 3; ++gate) {
        const float4* src = (const float4*)(whhL + (size_t)(uglob + gate * H_DIM) * H_DIM + 96 * p);
#pragma unroll
        for (int i = 0; i < 24; ++i) wr[gate][i] = src[i];
    }
    const float bhr  = bhhL[uglob], bhz = bhhL[uglob + H_DIM], bhn  = bhhL[uglob + 2 * H_DIM];
    const float bir  = bihL[uglob], biz = bihL[uglob + H_DIM], bin_ = bihL[uglob + 2 * H_DIM];

    // ---- prologue: w_ih -> LDS fp16 ----
    for (int rr = 0; rr < 24; ++rr) {
        const int r = wv * 24 + rr;            // 0..95
        const int u = r / 3, G = r % 3;
        const float* src = wihL + (size_t)(sub * UPB + u + G * H_DIM) * Din;
        _Float16* dst = wih16 + r * WIH_STRIDE;
        for (int k = lane; k < Din; k += 64) dst[k] = (_Float16)src[k];
    }
    __syncthreads();

    // ---- ih GEMV from hsd (fp16 weights), full 8-lane reduce ----
    auto ih_gemv = [&](float& gr, float& gz, float& gn) {
        float sr = 0.f, sz = 0.f, sn = 0.f;
        if (layer) {
            const float4* hs = (const float4*)(hsd + p * 100);
            const half8* w0 = (const half8*)(wih16 + (ulocal * 3 + 0) * WIH_STRIDE + 96 * p);
            const half8* w1 = (const half8*)(wih16 + (ulocal * 3 + 1) * WIH_STRIDE + 96 * p);
            const half8* w2 = (const half8*)(wih16 + (ulocal * 3 + 2) * WIH_STRIDE + 96 * p);
#pragma unroll
            for (int i = 0; i < 12; ++i) {
                const float4 ha = hs[2 * i], hb = hs[2 * i + 1];
                const half8 a0 = w0[i], a1 = w1[i], a2 = w2[i];
                sr += ha.x * (float)a0[0] + ha.y * (float)a0[1] + ha.z * (float)a0[2] + ha.w * (float)a0[3]
                    + hb.x * (float)a0[4] + hb.y * (float)a0[5] + hb.z * (float)a0[6] + hb.w * (float)a0[7];
                sz += ha.x * (float)a1[0] + ha.y * (float)a1[1] + ha.z * (float)a1[2] + ha.w * (float)a1[3]
                    + hb.x * (float)a1[4] + hb.y * (float)a1[5] + hb.z * (float)a1[6] + hb.w * (float)a1[7];
                sn += ha.x * (float)a2[0] + ha.y * (float)a2[1] + ha.z * (float)a2[2] + ha.w * (float)a2[3]
                    + hb.x * (float)a2[4] + hb.y * (float)a2[5] + hb.z * (float)a2[6] + hb.w * (float)a2[7];
            }
        } else {
            const float4* hs = (const float4*)(hsd + p * 52);
            const half8* w0 = (const half8*)(wih16 + (ulocal * 3 + 0) * WIH_STRIDE + 48 * p);
            const half8* w1 = (const half8*)(wih16 + (ulocal * 3 + 1) * WIH_STRIDE + 48 * p);
            const half8* w2 = (const half8*)(wih16 + (ulocal * 3 + 2) * WIH_STRIDE + 48 * p);
#pragma unroll
            for (int i = 0; i < 6; ++i) {
                const float4 ha = hs[2 * i], hb = hs[2 * i + 1];
                const half8 a0 = w0[i], a1 = w1[i], a2 = w2[i];
                sr += ha.x * (float)a0[0] + ha.y * (float)a0[1] + ha.z * (float)a0[2] + ha.w * (float)a0[3]
                    + hb.x * (float)a0[4] + hb.y * (float)a0[5] + hb.z * (float)a0[6] + hb.w * (float)a0[7];
                sz += ha.x * (float)a1[0] + ha.y * (float)a1[1] + ha.z * (float)a1[2] + ha.w * (float)a1[3]
                    + hb.x * (float)a1[4] + hb.y * (float)a1[5] + hb.z * (float)a1[6] + hb.w * (float)a1[7];
                sn += ha.x * (float)a2[0] + ha.y * (float)a2[1] + ha.z * (float)a2[2] + ha.w * (float)a2[3]
                    + hb.x * (float)a2[4] + hb.y * (float)a2[5] + hb.z * (float)a2[6] + hb.w * (float)a2[7];
            }
        }
#pragma unroll
        for (int off = 1; off <= 4; off <<= 1) {
            sr += __shfl_xor(sr, off, 64);
            sz += __shfl_xor(sz, off, 64);
            sn += __shfl_xor(sn, off, 64);
        }
        gr = sr + bir; gz = sz + biz; gn = sn + bin_;
    };

    // ---- prologue: gi(0) ----
    float gi_r, gi_z, gi_n;
    if (layer) {
        if (wv == 0) {                     // wait lower row 0 complete
            int idx = 0; unsigned tgt = 0;
            if (lane < 6) { idx = (layer - 1) * 6 + lane; tgt = 4u; }
            for (;;) {
                const unsigned v = __hip_atomic_load(&ctr[idx * CTR_STRIDE],
                                                     __ATOMIC_RELAXED, __HIP_MEMORY_SCOPE_AGENT);
                if (__all(v >= tgt)) break;
                __builtin_amdgcn_s_sleep(1);
            }
        }
        __syncthreads();
        const float* sr_ = ring + (size_t)((layer - 1) * RING) * H_DIM;
        const float a = ldg_dev(sr_ + tid), b = ldg_dev(sr_ + tid + 256), c = ldg_dev(sr_ + tid + 512);
        hsd[((tid      ) / 96) * 100 + ((tid      ) % 96)] = a;
        hsd[((tid + 256) / 96) * 100 + ((tid + 256) % 96)] = b;
        hsd[((tid + 512) / 96) * 100 + ((tid + 512) % 96)] = c;
    } else {
        for (int k = tid; k < IN0; k += NTHR) hsd[(k / 48) * 52 + (k % 48)] = x[k];
    }
    __syncthreads();
    ih_gemv(gi_r, gi_z, gi_n);

    const int my_ctr = (layer * 6 + (sub >> 2)) * CTR_STRIDE;

    for (int t = 0; t < T_SEQ; ++t) {
        // ---- poll: own >= 4t, lower >= 4(t+2), upper >= 4(t-RING+1) ----
        if (wv == 0) {
            int idx = 0; unsigned tgt = 0;
            if (lane < 6) {
                idx = layer * 6 + lane;             tgt = 4u * (unsigned)t;
            } else if (lane >= 8 && lane < 14 && layer > 0 && (t + 1) < T_SEQ) {
                idx = (layer - 1) * 6 + (lane - 8); tgt = 4u * (unsigned)(t + 2);
            } else if (lane >= 16 && lane < 22 && (layer + 1) < NLAYER && t >= RING) {
                idx = (layer + 1) * 6 + (lane - 16); tgt = 4u * (unsigned)(t - RING + 1);
            }
            for (;;) {
                const unsigned v = __hip_atomic_load(&ctr[idx * CTR_STRIDE],
                                                     __ATOMIC_RELAXED, __HIP_MEMORY_SCOPE_AGENT);
                if (__all(v >= tgt)) break;
                __builtin_amdgcn_s_sleep(1);
            }
        }
        __syncthreads();

        // ---- stage: critical h_l(t-1) and shadow h_{l-1}(t+1) / x(t+1) ----
        const bool have_c = (t > 0);
        const bool have_s = (t + 1) < T_SEQ;
        float cv0 = 0.f, cv1 = 0.f, cv2 = 0.f;
        float sv0 = 0.f, sv1 = 0.f, sv2 = 0.f;
        if (have_c) {
            const float* hr = (layer == NLAYER - 1)
                ? h9 + (size_t)(t - 1) * H_DIM
                : ring + (size_t)(layer * RING + ((t - 1) & (RING - 1))) * H_DIM;
            cv0 = ldg_dev(hr + tid);
            cv1 = ldg_dev(hr + tid + 256);
            cv2 = ldg_dev(hr + tid + 512);
        }
        if (have_s && layer) {
            const float* sr_ = ring + (size_t)((layer - 1) * RING + ((t + 1) & (RING - 1))) * H_DIM;
            sv0 = ldg_dev(sr_ + tid);
            sv1 = ldg_dev(sr_ + tid + 256);
            sv2 = ldg_dev(sr_ + tid + 512);
        }
        if (have_c) {
            hc[((tid      ) / 96) * 100 + ((tid      ) % 96)] = cv0;
            hc[((tid + 256) / 96) * 100 + ((tid + 256) % 96)] = cv1;
            hc[((tid + 512) / 96) * 100 + ((tid + 512) % 96)] = cv2;
        }
        if (have_s) {
            if (layer) {
                hsd[((tid      ) / 96) * 100 + ((tid      ) % 96)] = sv0;
                hsd[((tid + 256) / 96) * 100 + ((tid + 256) % 96)] = sv1;
                hsd[((tid + 512) / 96) * 100 + ((tid + 512) % 96)] = sv2;
            } else {
                for (int k = tid; k < IN0; k += NTHR)
                    hsd[(k / 48) * 52 + (k % 48)] = x[(size_t)(t + 1) * IN0 + k];
            }
        }
        __syncthreads();

        // ---- critical: recurrent GEMV from register weights ----
        float ar = 0.f, az = 0.f, an = 0.f;
        if (have_c) {
            const float4* hs = (const float4*)(hc + p * 100);
#pragma unroll
            for (int i = 0; i < 24; ++i) {
                const float4 h4 = hs[i];
                ar += h4.x * wr[0][i].x + h4.y * wr[0][i].y + h4.z * wr[0][i].z + h4.w * wr[0][i].w;
                az += h4.x * wr[1][i].x + h4.y * wr[1][i].y + h4.z * wr[1][i].z + h4.w * wr[1][i].w;
                an += h4.x * wr[2][i].x + h4.y * wr[2][i].y + h4.z * wr[2][i].z + h4.w * wr[2][i].w;
            }
        }
#pragma unroll
        for (int off = 1; off <= 4; off <<= 1) {
            ar += __shfl_xor(ar, off, 64);
            az += __shfl_xor(az, off, 64);
            an += __shfl_xor(an, off, 64);
        }
        if (p == 0) {
            const float hp = have_c ? hc[(uglob / 96) * 100 + (uglob % 96)] : 0.f;
            const float r = sigm(ar + bhr + gi_r);
            const float z = sigm(az + bhz + gi_z);
            const float n = tanhf(gi_n + r * (an + bhn));
            float* orow = (layer == NLAYER - 1)
                ? h9 + (size_t)t * H_DIM
                : ring + (size_t)(layer * RING + (t & (RING - 1))) * H_DIM;
            stg_dev(orow + uglob, (1.f - z) * n + z * hp);
        }

        // ---- arrive (syncthreads drains sc1 stores via vmcnt(0)) ----
        __syncthreads();
        if (tid == 0)
            __hip_atomic_fetch_add(&ctr[my_ctr], 1u,
                                   __ATOMIC_RELAXED, __HIP_MEMORY_SCOPE_AGENT);

        // ---- shadow: gi(t+1), overlaps bump->observe round trip ----
        if (have_s) ih_gemv(gi_r, gi_z, gi_n);
    }
}

extern "C" __global__ __launch_bounds__(NOUT, 1) void fc_head(
    const float* __restrict__ h,
    const float* __restrict__ fw,
    const float* __restrict__ fb,
    float* __restrict__ out)
{
    __shared__ float hs[H_DIM];
    const int t = blockIdx.x;
    const float* hr = h + (size_t)t * H_DIM;
    for (int k = threadIdx.x; k < H_DIM; k += NOUT) hs[k] = hr[k];
    __syncthreads();

    const int o = threadIdx.x;
    const float4* wr4 = (const float4*)(fw + (size_t)o * H_DIM);
    const float4* hs4 = (const float4*)hs;
    float acc = fb[o];
#pragma unroll 8
    for (int k = 0; k < H_DIM / 4; ++k) {
        const float4 w = wr4[k], hv = hs4[k];
        acc += w.x * hv.x + w.y * hv.y + w.z * hv.z + w.w * hv.w;
    }
    out[(size_t)t * NOUT + o] = acc;
}

extern "C" void kernel_launch(void* const* d_in, const int* in_sizes, int n_in,
                              void* d_out, int out_size, void* d_ws, size_t ws_size,
                              hipStream_t stream)
{
    const float* x    = (const float*)d_in[0];
    const float* wih0 = (const float*)d_in[1];
    const float* whh0 = (const float*)d_in[2];
    const float* bih0 = (const float*)d_in[3];
    const float* bhh0 = (const float*)d_in[4];
    const float* wihS = (const float*)d_in[5];
    const float* whhS = (const float*)d_in[6];
    const float* bihS = (const float*)d_in[7];
    const float* bhhS = (const float*)d_in[8];
    const float* fcw  = (const float*)d_in[9];
    const float* fcb  = (const float*)d_in[10];

    char* ws = (char*)d_ws;
    unsigned int* ctr = (unsigned int*)ws;                     // 64 KB counter region
    float* ring = (float*)(ws + 65536);                        // 9 x 16 x 768 fp32 = 442,368 B
    float* h9   = (float*)(ws + 65536 + 9 * RING * H_DIM * 4); // 2048 x 768 fp32

    hipMemsetAsync(ctr, 0, 65536, stream);

    hipLaunchKernelGGL(gru_flow, dim3(NBLK), dim3(NTHR), 0, stream,
                       x, wih0, whh0, bih0, bhh0, wihS, whhS, bihS, bhhS,
                       ring, h9, ctr);

    hipLaunchKernelGGL(fc_head, dim3(T_SEQ), dim3(NOUT), 0, stream,
                       h9, fcw, fcb, (float*)d_out);
}